// Round 1
// baseline (432.824 us; speedup 1.0000x reference)
//
#include <hip/hip_runtime.h>
#include <hip/hip_bf16.h>

// GCN: 3x GraphConv (left norm) + policy/value heads.
// Strategy: aggregate-first (linearity: segsum(h[src]*w)@W == segsum((h@W)[src]*w)),
// CSR-by-dst counting sort per call (no float atomics in aggregation),
// fp32 tiled GEMM (no fp32 MFMA on CDNA4).

#define N_NODES_F 128   // IN_F
#define HIDF 256

// ---------------- preprocessing ----------------

__global__ void hist_kernel(const int* __restrict__ src, const int* __restrict__ dst,
                            float* __restrict__ deg, int* __restrict__ counts, int E) {
    int e = blockIdx.x * blockDim.x + threadIdx.x;
    if (e >= E) return;
    atomicAdd(&deg[src[e]], 1.0f);
    atomicAdd(&counts[dst[e]], 1);
}

// single-block exclusive scan: offsets[0..n], offsets[n] = total
__global__ __launch_bounds__(1024) void scan_kernel(const int* __restrict__ counts,
                                                    int* __restrict__ offsets, int n) {
    __shared__ int partial[1024];
    int tid = threadIdx.x;
    int chunk = (n + 1023) / 1024;
    int start = tid * chunk;
    int s = 0;
    for (int i = 0; i < chunk; i++) {
        int idx = start + i;
        if (idx < n) s += counts[idx];
    }
    partial[tid] = s;
    __syncthreads();
    for (int off = 1; off < 1024; off <<= 1) {
        int v = 0;
        if (tid >= off) v = partial[tid - off];
        __syncthreads();
        partial[tid] += v;
        __syncthreads();
    }
    int run = (tid > 0) ? partial[tid - 1] : 0;
    for (int i = 0; i < chunk; i++) {
        int idx = start + i;
        if (idx < n) { offsets[idx] = run; run += counts[idx]; }
    }
    if (tid == 1023) offsets[n] = partial[1023];
}

__global__ void build_edges_kernel(const int* __restrict__ src, const int* __restrict__ dst,
                                   const float* __restrict__ deg, const int* __restrict__ offsets,
                                   int* __restrict__ cursor, int* __restrict__ ssrc,
                                   float* __restrict__ sw, int E) {
    int e = blockIdx.x * blockDim.x + threadIdx.x;
    if (e >= E) return;
    int s = src[e], d = dst[e];
    int pos = offsets[d] + atomicAdd(&cursor[d], 1);
    ssrc[pos] = s;
    sw[pos] = 1.0f / deg[s];   // deg[s] >= 1: edge e itself contributes to deg[src[e]]
}

// ---------------- aggregation ----------------
// one block per dst node; thread t owns feature t; loop over CSR in-edges.
template <int F>
__global__ __launch_bounds__(256) void aggregate_kernel(
    const float* __restrict__ h, const int* __restrict__ offsets,
    const int* __restrict__ ssrc, const float* __restrict__ sw,
    float* __restrict__ out) {
    int node = blockIdx.x;
    int t = threadIdx.x;              // [0, F)
    int beg = offsets[node], end = offsets[node + 1];
    float acc = 0.0f;
    for (int e = beg; e < end; ++e) {
        int s = ssrc[e];
        float w = sw[e];
        acc += h[(size_t)s * F + t] * w;
    }
    out[(size_t)node * F + t] = acc;   // full write: zero-in-degree nodes get 0
}

// ---------------- fp32 GEMM: C = act(A[M,K] @ B[K,N] + bias) ----------------
// 64x64 tile, 4x4 per thread, BK=16, LDS rows padded to 68 floats.
__global__ __launch_bounds__(256) void gemm_bias_act(
    const float* __restrict__ A, const float* __restrict__ B,
    const float* __restrict__ bias, float* __restrict__ C,
    int M, int K, int NN, int relu) {
    __shared__ float As[16][68];
    __shared__ float Bs[16][68];

    const int tid = threadIdx.x;
    const int tx = tid & 15;          // col group
    const int ty = tid >> 4;          // row group
    const int r0 = blockIdx.y * 64;
    const int c0 = blockIdx.x * 64;

    const int lm = tid >> 2;          // 0..63 (A-load row)
    const int lk = (tid & 3) * 4;     // 0,4,8,12 (A-load k base)
    const int ln = tid & 63;          // B-load col
    const int kb = (tid >> 6) * 4;    // B-load k base (0,4,8,12)

    float acc[4][4];
#pragma unroll
    for (int r = 0; r < 4; r++)
#pragma unroll
        for (int c = 0; c < 4; c++) acc[r][c] = 0.0f;

    for (int k0 = 0; k0 < K; k0 += 16) {
        // A tile: As[k][m] = A[r0+m][k0+k]
        float4 av = make_float4(0.f, 0.f, 0.f, 0.f);
        int arow = r0 + lm;
        if (arow < M) av = *(const float4*)&A[(size_t)arow * K + k0 + lk];
        As[lk + 0][lm] = av.x;
        As[lk + 1][lm] = av.y;
        As[lk + 2][lm] = av.z;
        As[lk + 3][lm] = av.w;
        // B tile: Bs[k][n] = B[k0+k][c0+n]
#pragma unroll
        for (int j = 0; j < 4; j++) {
            int k = kb + j;
            Bs[k][ln] = B[(size_t)(k0 + k) * NN + c0 + ln];
        }
        __syncthreads();
#pragma unroll
        for (int k = 0; k < 16; k++) {
            float4 a = *(const float4*)&As[k][ty * 4];
            float4 b = *(const float4*)&Bs[k][tx * 4];
            float ar[4] = {a.x, a.y, a.z, a.w};
            float bc[4] = {b.x, b.y, b.z, b.w};
#pragma unroll
            for (int r = 0; r < 4; r++)
#pragma unroll
                for (int c = 0; c < 4; c++) acc[r][c] += ar[r] * bc[c];
        }
        __syncthreads();
    }

    float bv[4];
#pragma unroll
    for (int c = 0; c < 4; c++) bv[c] = bias[c0 + tx * 4 + c];

#pragma unroll
    for (int r = 0; r < 4; r++) {
        int row = r0 + ty * 4 + r;
        if (row < M) {
            float4 o;
            float v0 = acc[r][0] + bv[0];
            float v1 = acc[r][1] + bv[1];
            float v2 = acc[r][2] + bv[2];
            float v3 = acc[r][3] + bv[3];
            if (relu) {
                v0 = fmaxf(v0, 0.f); v1 = fmaxf(v1, 0.f);
                v2 = fmaxf(v2, 0.f); v3 = fmaxf(v3, 0.f);
            }
            o.x = v0; o.y = v1; o.z = v2; o.w = v3;
            *(float4*)&C[(size_t)row * NN + c0 + tx * 4] = o;
        }
    }
}

// ---------------- heads ----------------

__global__ __launch_bounds__(256) void colsum_kernel(const float* __restrict__ h,
                                                     float* __restrict__ colsum, int n) {
    int t = threadIdx.x;  // 256
    float acc = 0.0f;
    for (int r = blockIdx.x; r < n; r += gridDim.x)
        acc += h[(size_t)r * HIDF + t];
    atomicAdd(&colsum[t], acc);
}

__global__ __launch_bounds__(256) void pi_kernel(const float* __restrict__ h,
                                                 const float* __restrict__ Wp,
                                                 const float* __restrict__ bp,
                                                 float* __restrict__ out, int n) {
    int lane = threadIdx.x & 63;
    int wid = threadIdx.x >> 6;
    int node = blockIdx.x * 4 + wid;
    if (node >= n) return;
    const float* row = h + (size_t)node * HIDF;
    float v = 0.0f;
#pragma unroll
    for (int i = 0; i < 4; i++) v += row[lane + 64 * i] * Wp[lane + 64 * i];
#pragma unroll
    for (int o = 32; o > 0; o >>= 1) v += __shfl_down(v, o, 64);
    if (lane == 0) out[node] = v + bp[0];
}

__global__ void v_kernel(const float* __restrict__ colsum, const float* __restrict__ Wv,
                         const float* __restrict__ bv, float* __restrict__ out, float invN) {
    int lane = threadIdx.x;  // 64
    float v = 0.0f;
#pragma unroll
    for (int i = 0; i < 4; i++) v += colsum[lane + 64 * i] * Wv[lane + 64 * i];
#pragma unroll
    for (int o = 32; o > 0; o >>= 1) v += __shfl_down(v, o, 64);
    if (lane == 0) out[0] = v * invN + bv[0];
}

// ---------------- launch ----------------

extern "C" void kernel_launch(void* const* d_in, const int* in_sizes, int n_in,
                              void* d_out, int out_size, void* d_ws, size_t ws_size,
                              hipStream_t stream) {
    const float* features = (const float*)d_in[0];
    const int*   src      = (const int*)d_in[1];
    const int*   dst      = (const int*)d_in[2];
    const float* W1 = (const float*)d_in[3];
    const float* b1 = (const float*)d_in[4];
    const float* W2 = (const float*)d_in[5];
    const float* b2 = (const float*)d_in[6];
    const float* W3 = (const float*)d_in[7];
    const float* b3 = (const float*)d_in[8];
    const float* Wp = (const float*)d_in[9];
    const float* bp = (const float*)d_in[10];
    const float* Wv = (const float*)d_in[11];
    const float* bv = (const float*)d_in[12];
    float* out = (float*)d_out;

    const int N = in_sizes[0] / N_NODES_F;   // 10000
    const int E = in_sizes[1];               // 320000

    // workspace layout
    char* p = (char*)d_ws;
    auto alloc = [&](size_t bytes) -> void* {
        void* r = (void*)p;
        p += (bytes + 511) & ~(size_t)511;
        return r;
    };
    float* deg     = (float*)alloc((size_t)N * 4);
    int*   counts  = (int*)alloc((size_t)N * 4);
    int*   offsets = (int*)alloc((size_t)(N + 1) * 4);
    int*   cursor  = (int*)alloc((size_t)N * 4);
    int*   ssrc    = (int*)alloc((size_t)E * 4);
    float* sw      = (float*)alloc((size_t)E * 4);
    float* bufA    = (float*)alloc((size_t)N * HIDF * 4);
    float* bufB    = (float*)alloc((size_t)N * HIDF * 4);
    float* colsum  = (float*)alloc(HIDF * 4);

    // zero the accumulated buffers (ws is poisoned 0xAA every call)
    hipMemsetAsync(deg,    0, (size_t)N * 4, stream);
    hipMemsetAsync(counts, 0, (size_t)N * 4, stream);
    hipMemsetAsync(cursor, 0, (size_t)N * 4, stream);
    hipMemsetAsync(colsum, 0, HIDF * 4, stream);

    const int eb = (E + 255) / 256;
    hist_kernel<<<eb, 256, 0, stream>>>(src, dst, deg, counts, E);
    scan_kernel<<<1, 1024, 0, stream>>>(counts, offsets, N);
    build_edges_kernel<<<eb, 256, 0, stream>>>(src, dst, deg, offsets, cursor, ssrc, sw, E);

    dim3 ggrid(4, (N + 63) / 64);

    // layer 1: aggregate features (F=128), then GEMM 128->256 + relu
    aggregate_kernel<128><<<N, 128, 0, stream>>>(features, offsets, ssrc, sw, bufA);
    gemm_bias_act<<<ggrid, 256, 0, stream>>>(bufA, W1, b1, bufB, N, 128, 256, 1);
    // layer 2
    aggregate_kernel<256><<<N, 256, 0, stream>>>(bufB, offsets, ssrc, sw, bufA);
    gemm_bias_act<<<ggrid, 256, 0, stream>>>(bufA, W2, b2, bufB, N, 256, 256, 1);
    // layer 3 (no relu)
    aggregate_kernel<256><<<N, 256, 0, stream>>>(bufB, offsets, ssrc, sw, bufA);
    gemm_bias_act<<<ggrid, 256, 0, stream>>>(bufA, W3, b3, bufB, N, 256, 256, 0);

    // heads
    colsum_kernel<<<80, 256, 0, stream>>>(bufB, colsum, N);
    pi_kernel<<<(N + 3) / 4, 256, 0, stream>>>(bufB, Wp, bp, out, N);
    v_kernel<<<1, 64, 0, stream>>>(colsum, Wv, bv, out + N, 1.0f / (float)N);
}

// Round 2
// 296.903 us; speedup vs baseline: 1.4578x; 1.4578x over previous
//
#include <hip/hip_runtime.h>
#include <hip/hip_bf16.h>
#include <stdint.h>

// GCN: 3x GraphConv (left norm) + heads, bf16 internal / fp32 accumulate.
// - aggregate-first (linearity), 1/deg folded into producer rows
// - CSR-by-dst counting sort, aggregation = plain bf16 gather-sum (no atomics)
// - LDS-free MFMA bf16 GEMM: A frags direct from row-major buffer,
//   B pre-swizzled to fragment order (Bsw[k/32][n][k%32])

#define INF 128
#define HIDF 256

typedef __attribute__((ext_vector_type(8))) short bf16x8;   // 8 bf16 (4 VGPRs)
typedef __attribute__((ext_vector_type(4))) float f32x4;

__device__ __forceinline__ float bf2f(uint16_t u) {
    union { uint32_t i; float f; } x; x.i = ((uint32_t)u) << 16; return x.f;
}
__device__ __forceinline__ uint16_t f2bf(float f) {   // round-to-nearest-even
    union { float f; uint32_t i; } x; x.f = f;
    uint32_t r = x.i + 0x7fffu + ((x.i >> 16) & 1u);
    return (uint16_t)(r >> 16);
}

// ---------------- preprocessing ----------------

__global__ void hist_kernel(const int* __restrict__ src, const int* __restrict__ dst,
                            int* __restrict__ odeg, int* __restrict__ counts, int E) {
    int e = blockIdx.x * blockDim.x + threadIdx.x;
    if (e >= E) return;
    atomicAdd(&odeg[src[e]], 1);
    atomicAdd(&counts[dst[e]], 1);
}

__global__ void invdeg_kernel(const int* __restrict__ odeg, float* __restrict__ inv, int n) {
    int i = blockIdx.x * blockDim.x + threadIdx.x;
    if (i >= n) return;
    int d = odeg[i];
    inv[i] = d > 0 ? 1.0f / (float)d : 0.0f;
}

__global__ __launch_bounds__(1024) void scan_kernel(const int* __restrict__ counts,
                                                    int* __restrict__ offsets, int n) {
    __shared__ int partial[1024];
    int tid = threadIdx.x;
    int chunk = (n + 1023) / 1024;
    int start = tid * chunk;
    int s = 0;
    for (int i = 0; i < chunk; i++) {
        int idx = start + i;
        if (idx < n) s += counts[idx];
    }
    partial[tid] = s;
    __syncthreads();
    for (int off = 1; off < 1024; off <<= 1) {
        int v = 0;
        if (tid >= off) v = partial[tid - off];
        __syncthreads();
        partial[tid] += v;
        __syncthreads();
    }
    int run = (tid > 0) ? partial[tid - 1] : 0;
    for (int i = 0; i < chunk; i++) {
        int idx = start + i;
        if (idx < n) { offsets[idx] = run; run += counts[idx]; }
    }
    if (tid == 1023) offsets[n] = partial[1023];
}

__global__ void build_edges_kernel(const int* __restrict__ src, const int* __restrict__ dst,
                                   const int* __restrict__ offsets, int* __restrict__ cursor,
                                   int* __restrict__ ssrc, int E) {
    int e = blockIdx.x * blockDim.x + threadIdx.x;
    if (e >= E) return;
    int d = dst[e];
    int pos = offsets[d] + atomicAdd(&cursor[d], 1);
    ssrc[pos] = src[e];
}

// features fp32 [N x 128] -> bf16 scaled by inv_deg[row]; 4 elems/thread
__global__ void convf_kernel(const float* __restrict__ f, const float* __restrict__ inv,
                             uint16_t* __restrict__ out, int total) {
    int base = (blockIdx.x * blockDim.x + threadIdx.x) * 4;
    if (base >= total) return;
    int row = base >> 7;   // /128
    float s = inv[row];
    float4 v = *(const float4*)&f[base];
    ushort4 o;
    o.x = f2bf(v.x * s); o.y = f2bf(v.y * s);
    o.z = f2bf(v.z * s); o.w = f2bf(v.w * s);
    *(ushort4*)&out[base] = o;
}

// W [K x 256] fp32 -> Bsw[k/32][n][k%32] bf16 (fragment-friendly panels)
__global__ void swz_kernel(const float* __restrict__ W, uint16_t* __restrict__ out, int total) {
    int idx = blockIdx.x * blockDim.x + threadIdx.x;
    if (idx >= total) return;
    int k = idx >> 8;          // /256
    int n = idx & 255;
    out[((size_t)(k >> 5) * 256 + n) * 32 + (k & 31)] = f2bf(W[idx]);
}

// ---------------- aggregation: plain sum of gathered (pre-scaled) bf16 rows ----
// wave per node, 4 nodes per 256-thread block, 4-edge unroll for MLP.

__global__ __launch_bounds__(256) void aggregate256(
    const uint16_t* __restrict__ hs, const int* __restrict__ offsets,
    const int* __restrict__ ssrc, uint16_t* __restrict__ out, int n) {
    int lane = threadIdx.x & 63, wid = threadIdx.x >> 6;
    int node = blockIdx.x * 4 + wid;
    if (node >= n) return;
    int beg = offsets[node], end = offsets[node + 1];
    float a0 = 0, a1 = 0, a2 = 0, a3 = 0;
    const size_t col = (size_t)lane * 4;
    int e = beg;
    for (; e + 4 <= end; e += 4) {
        int s0 = ssrc[e], s1 = ssrc[e + 1], s2 = ssrc[e + 2], s3 = ssrc[e + 3];
        ushort4 r0 = *(const ushort4*)&hs[(size_t)s0 * 256 + col];
        ushort4 r1 = *(const ushort4*)&hs[(size_t)s1 * 256 + col];
        ushort4 r2 = *(const ushort4*)&hs[(size_t)s2 * 256 + col];
        ushort4 r3 = *(const ushort4*)&hs[(size_t)s3 * 256 + col];
        a0 += bf2f(r0.x) + bf2f(r1.x) + bf2f(r2.x) + bf2f(r3.x);
        a1 += bf2f(r0.y) + bf2f(r1.y) + bf2f(r2.y) + bf2f(r3.y);
        a2 += bf2f(r0.z) + bf2f(r1.z) + bf2f(r2.z) + bf2f(r3.z);
        a3 += bf2f(r0.w) + bf2f(r1.w) + bf2f(r2.w) + bf2f(r3.w);
    }
    for (; e < end; e++) {
        ushort4 r = *(const ushort4*)&hs[(size_t)ssrc[e] * 256 + col];
        a0 += bf2f(r.x); a1 += bf2f(r.y); a2 += bf2f(r.z); a3 += bf2f(r.w);
    }
    ushort4 o; o.x = f2bf(a0); o.y = f2bf(a1); o.z = f2bf(a2); o.w = f2bf(a3);
    *(ushort4*)&out[(size_t)node * 256 + col] = o;
}

__global__ __launch_bounds__(256) void aggregate128(
    const uint16_t* __restrict__ hs, const int* __restrict__ offsets,
    const int* __restrict__ ssrc, uint16_t* __restrict__ out, int n) {
    int lane = threadIdx.x & 63, wid = threadIdx.x >> 6;
    int node = blockIdx.x * 4 + wid;
    if (node >= n) return;
    int beg = offsets[node], end = offsets[node + 1];
    float a0 = 0, a1 = 0;
    const size_t col = (size_t)lane * 2;
    int e = beg;
    for (; e + 4 <= end; e += 4) {
        int s0 = ssrc[e], s1 = ssrc[e + 1], s2 = ssrc[e + 2], s3 = ssrc[e + 3];
        ushort2 r0 = *(const ushort2*)&hs[(size_t)s0 * 128 + col];
        ushort2 r1 = *(const ushort2*)&hs[(size_t)s1 * 128 + col];
        ushort2 r2 = *(const ushort2*)&hs[(size_t)s2 * 128 + col];
        ushort2 r3 = *(const ushort2*)&hs[(size_t)s3 * 128 + col];
        a0 += bf2f(r0.x) + bf2f(r1.x) + bf2f(r2.x) + bf2f(r3.x);
        a1 += bf2f(r0.y) + bf2f(r1.y) + bf2f(r2.y) + bf2f(r3.y);
    }
    for (; e < end; e++) {
        ushort2 r = *(const ushort2*)&hs[(size_t)ssrc[e] * 128 + col];
        a0 += bf2f(r.x); a1 += bf2f(r.y);
    }
    ushort2 o; o.x = f2bf(a0); o.y = f2bf(a1);
    *(ushort2*)&out[(size_t)node * 128 + col] = o;
}

// ---------------- MFMA bf16 GEMM, LDS-free ----------------
// C[M x 256] = A[M x K] @ B[K x 256]; A row-major bf16, B pre-swizzled.
// Block: 256 thr = 4 waves (2x2), tile 64x64; wave: 32x32 via 2x2 mfma_16x16x32.
// mode 1: relu then * inv_deg[row]; mode 0: plain. Output bf16.

__global__ __launch_bounds__(256) void gemm_mfma(
    const uint16_t* __restrict__ A, const uint16_t* __restrict__ Bsw,
    const float* __restrict__ bias, const float* __restrict__ inv,
    uint16_t* __restrict__ C, int M, int K, int mode) {
    const int lane = threadIdx.x & 63;
    const int wid = threadIdx.x >> 6;
    const int wr = wid >> 1, wc = wid & 1;
    const int quad = lane >> 4;
    const int l16 = lane & 15;

    const int m_base = blockIdx.y * 64 + wr * 32;
    const int n_base = blockIdx.x * 64 + wc * 32;

    const int r0 = m_base + l16;          // rows for a-frag mi=0
    const int r1 = m_base + 16 + l16;     // mi=1
    const int r0c = min(r0, M - 1);
    const int r1c = min(r1, M - 1);

    const uint16_t* a0p = A + (size_t)r0c * K + quad * 8;
    const uint16_t* a1p = A + (size_t)r1c * K + quad * 8;
    const uint16_t* b0p = Bsw + ((size_t)(n_base + l16)) * 32 + quad * 8;
    const uint16_t* b1p = Bsw + ((size_t)(n_base + 16 + l16)) * 32 + quad * 8;

    f32x4 acc00 = {0, 0, 0, 0}, acc01 = {0, 0, 0, 0};
    f32x4 acc10 = {0, 0, 0, 0}, acc11 = {0, 0, 0, 0};

    const int panels = K >> 5;
#pragma unroll 4
    for (int p = 0; p < panels; p++) {
        bf16x8 a0 = *(const bf16x8*)(a0p + p * 32);
        bf16x8 a1 = *(const bf16x8*)(a1p + p * 32);
        bf16x8 b0 = *(const bf16x8*)(b0p + (size_t)p * 256 * 32);
        bf16x8 b1 = *(const bf16x8*)(b1p + (size_t)p * 256 * 32);
        acc00 = __builtin_amdgcn_mfma_f32_16x16x32_bf16(a0, b0, acc00, 0, 0, 0);
        acc01 = __builtin_amdgcn_mfma_f32_16x16x32_bf16(a0, b1, acc01, 0, 0, 0);
        acc10 = __builtin_amdgcn_mfma_f32_16x16x32_bf16(a1, b0, acc10, 0, 0, 0);
        acc11 = __builtin_amdgcn_mfma_f32_16x16x32_bf16(a1, b1, acc11, 0, 0, 0);
    }

    // epilogue: C/D layout col = lane&15, row = quad*4 + reg
    const int col0 = n_base + l16;
    const int col1 = n_base + 16 + l16;
    const float bv0 = bias[col0];
    const float bv1 = bias[col1];
#pragma unroll
    for (int reg = 0; reg < 4; reg++) {
        int row0 = m_base + quad * 4 + reg;
        int row1 = m_base + 16 + quad * 4 + reg;
        if (row0 < M) {
            float v00 = acc00[reg] + bv0;
            float v01 = acc01[reg] + bv1;
            if (mode) { float s = inv[row0]; v00 = fmaxf(v00, 0.f) * s; v01 = fmaxf(v01, 0.f) * s; }
            C[(size_t)row0 * 256 + col0] = f2bf(v00);
            C[(size_t)row0 * 256 + col1] = f2bf(v01);
        }
        if (row1 < M) {
            float v10 = acc10[reg] + bv0;
            float v11 = acc11[reg] + bv1;
            if (mode) { float s = inv[row1]; v10 = fmaxf(v10, 0.f) * s; v11 = fmaxf(v11, 0.f) * s; }
            C[(size_t)row1 * 256 + col0] = f2bf(v10);
            C[(size_t)row1 * 256 + col1] = f2bf(v11);
        }
    }
}

// ---------------- heads ----------------

__global__ __launch_bounds__(256) void colsum_kernel(const uint16_t* __restrict__ h,
                                                     float* __restrict__ colsum, int n) {
    int t = threadIdx.x;  // 256
    float acc = 0.0f;
    for (int r = blockIdx.x; r < n; r += gridDim.x)
        acc += bf2f(h[(size_t)r * 256 + t]);
    atomicAdd(&colsum[t], acc);
}

__global__ __launch_bounds__(256) void pi_kernel(const uint16_t* __restrict__ h,
                                                 const float* __restrict__ Wp,
                                                 const float* __restrict__ bp,
                                                 float* __restrict__ out, int n) {
    int lane = threadIdx.x & 63;
    int wid = threadIdx.x >> 6;
    int node = blockIdx.x * 4 + wid;
    if (node >= n) return;
    ushort4 r = *(const ushort4*)&h[(size_t)node * 256 + lane * 4];
    float4 w = *(const float4*)&Wp[lane * 4];
    float v = bf2f(r.x) * w.x + bf2f(r.y) * w.y + bf2f(r.z) * w.z + bf2f(r.w) * w.w;
#pragma unroll
    for (int o = 32; o > 0; o >>= 1) v += __shfl_down(v, o, 64);
    if (lane == 0) out[node] = v + bp[0];
}

__global__ void v_kernel(const float* __restrict__ colsum, const float* __restrict__ Wv,
                         const float* __restrict__ bv, float* __restrict__ out, float invN) {
    int lane = threadIdx.x;  // 64
    float v = 0.0f;
#pragma unroll
    for (int i = 0; i < 4; i++) v += colsum[lane + 64 * i] * Wv[lane + 64 * i];
#pragma unroll
    for (int o = 32; o > 0; o >>= 1) v += __shfl_down(v, o, 64);
    if (lane == 0) out[0] = v * invN + bv[0];
}

// ---------------- launch ----------------

extern "C" void kernel_launch(void* const* d_in, const int* in_sizes, int n_in,
                              void* d_out, int out_size, void* d_ws, size_t ws_size,
                              hipStream_t stream) {
    const float* features = (const float*)d_in[0];
    const int*   src      = (const int*)d_in[1];
    const int*   dst      = (const int*)d_in[2];
    const float* W1 = (const float*)d_in[3];
    const float* b1 = (const float*)d_in[4];
    const float* W2 = (const float*)d_in[5];
    const float* b2 = (const float*)d_in[6];
    const float* W3 = (const float*)d_in[7];
    const float* b3 = (const float*)d_in[8];
    const float* Wp = (const float*)d_in[9];
    const float* bp = (const float*)d_in[10];
    const float* Wv = (const float*)d_in[11];
    const float* bv = (const float*)d_in[12];
    float* out = (float*)d_out;

    const int N = in_sizes[0] / INF;   // 10000
    const int E = in_sizes[1];         // 320000

    char* p = (char*)d_ws;
    auto alloc = [&](size_t bytes) -> void* {
        void* r = (void*)p;
        p += (bytes + 511) & ~(size_t)511;
        return r;
    };
    int*      odeg    = (int*)alloc((size_t)N * 4);
    int*      counts  = (int*)alloc((size_t)N * 4);
    int*      offsets = (int*)alloc((size_t)(N + 1) * 4);
    int*      cursor  = (int*)alloc((size_t)N * 4);
    int*      ssrc    = (int*)alloc((size_t)E * 4);
    float*    invd    = (float*)alloc((size_t)N * 4);
    uint16_t* fbf     = (uint16_t*)alloc((size_t)N * INF * 2);
    uint16_t* ab      = (uint16_t*)alloc((size_t)N * HIDF * 2);  // aggregated (GEMM A)
    uint16_t* hb      = (uint16_t*)alloc((size_t)N * HIDF * 2);  // layer output
    uint16_t* W1s     = (uint16_t*)alloc((size_t)INF * HIDF * 2);
    uint16_t* W2s     = (uint16_t*)alloc((size_t)HIDF * HIDF * 2);
    uint16_t* W3s     = (uint16_t*)alloc((size_t)HIDF * HIDF * 2);
    float*    colsum  = (float*)alloc(HIDF * 4);

    hipMemsetAsync(odeg,   0, (size_t)N * 4, stream);
    hipMemsetAsync(counts, 0, (size_t)N * 4, stream);
    hipMemsetAsync(cursor, 0, (size_t)N * 4, stream);
    hipMemsetAsync(colsum, 0, HIDF * 4, stream);

    const int eb = (E + 255) / 256;
    hist_kernel<<<eb, 256, 0, stream>>>(src, dst, odeg, counts, E);
    scan_kernel<<<1, 1024, 0, stream>>>(counts, offsets, N);
    build_edges_kernel<<<eb, 256, 0, stream>>>(src, dst, offsets, cursor, ssrc, E);
    invdeg_kernel<<<(N + 255) / 256, 256, 0, stream>>>(odeg, invd, N);
    convf_kernel<<<(N * INF / 4 + 255) / 256, 256, 0, stream>>>(features, invd, fbf, N * INF);
    swz_kernel<<<(INF * HIDF + 255) / 256, 256, 0, stream>>>(W1, W1s, INF * HIDF);
    swz_kernel<<<(HIDF * HIDF + 255) / 256, 256, 0, stream>>>(W2, W2s, HIDF * HIDF);
    swz_kernel<<<(HIDF * HIDF + 255) / 256, 256, 0, stream>>>(W3, W3s, HIDF * HIDF);

    dim3 ggrid(4, (N + 63) / 64);   // 4 x 157

    // layer 1
    aggregate128<<<(N + 3) / 4, 256, 0, stream>>>(fbf, offsets, ssrc, ab, N);
    gemm_mfma<<<ggrid, 256, 0, stream>>>(ab, W1s, b1, invd, hb, N, INF, 1);
    // layer 2
    aggregate256<<<(N + 3) / 4, 256, 0, stream>>>(hb, offsets, ssrc, ab, N);
    gemm_mfma<<<ggrid, 256, 0, stream>>>(ab, W2s, b2, invd, hb, N, HIDF, 1);
    // layer 3 (no relu, no scale)
    aggregate256<<<(N + 3) / 4, 256, 0, stream>>>(hb, offsets, ssrc, ab, N);
    gemm_mfma<<<ggrid, 256, 0, stream>>>(ab, W3s, b3, invd, hb, N, HIDF, 0);

    // heads
    colsum_kernel<<<80, 256, 0, stream>>>(hb, colsum, N);
    pi_kernel<<<(N + 3) / 4, 256, 0, stream>>>(hb, Wp, bp, out, N);
    v_kernel<<<1, 64, 0, stream>>>(colsum, Wv, bv, out + N, 1.0f / (float)N);
}

// Round 3
// 239.484 us; speedup vs baseline: 1.8073x; 1.2398x over previous
//
#include <hip/hip_runtime.h>
#include <hip/hip_bf16.h>
#include <stdint.h>

// GCN: 3x GraphConv (left norm) + heads, bf16 internal / fp32 accumulate.
// - aggregate-first, 1/deg folded into producer rows (epilogue / feature-convert)
// - CSR-by-dst counting sort; aggregation = plain bf16 gather-sum, 16B loads,
//   wave split in halves/quarters for 2-4 edges in flight per issue slot
// - LDS-free MFMA bf16 GEMM (B pre-swizzled to fragment order)
// - layer-3 GEMM fuses BOTH heads in the epilogue (no h3 materialization)

#define INF 128
#define HIDF 256

typedef __attribute__((ext_vector_type(8))) short bf16x8;   // 8 bf16 (4 VGPRs)
typedef __attribute__((ext_vector_type(4))) float f32x4;

__device__ __forceinline__ float bf_lo(uint32_t u) {
    union { uint32_t i; float f; } x; x.i = u << 16; return x.f;
}
__device__ __forceinline__ float bf_hi(uint32_t u) {
    union { uint32_t i; float f; } x; x.i = u & 0xffff0000u; return x.f;
}
__device__ __forceinline__ uint16_t f2bf(float f) {   // round-to-nearest-even
    union { float f; uint32_t i; } x; x.f = f;
    uint32_t r = x.i + 0x7fffu + ((x.i >> 16) & 1u);
    return (uint16_t)(r >> 16);
}
__device__ __forceinline__ uint32_t pack2(float a, float b) {
    return (uint32_t)f2bf(a) | ((uint32_t)f2bf(b) << 16);
}

// ---------------- preprocessing ----------------

__global__ void hist_kernel(const int* __restrict__ src, const int* __restrict__ dst,
                            int* __restrict__ odeg, int* __restrict__ counts, int E) {
    int e = blockIdx.x * blockDim.x + threadIdx.x;
    if (e >= E) return;
    atomicAdd(&odeg[src[e]], 1);
    atomicAdd(&counts[dst[e]], 1);
}

// scan of counts -> offsets[0..n]; also computes inv_deg (merged invdeg kernel)
__global__ __launch_bounds__(1024) void scan_kernel(const int* __restrict__ counts,
                                                    int* __restrict__ offsets,
                                                    const int* __restrict__ odeg,
                                                    float* __restrict__ inv, int n) {
    __shared__ int partial[1024];
    int tid = threadIdx.x;
    int chunk = (n + 1023) / 1024;
    int start = tid * chunk;
    int s = 0;
    for (int i = 0; i < chunk; i++) {
        int idx = start + i;
        if (idx < n) {
            s += counts[idx];
            int d = odeg[idx];
            inv[idx] = d > 0 ? 1.0f / (float)d : 0.0f;
        }
    }
    partial[tid] = s;
    __syncthreads();
    for (int off = 1; off < 1024; off <<= 1) {
        int v = 0;
        if (tid >= off) v = partial[tid - off];
        __syncthreads();
        partial[tid] += v;
        __syncthreads();
    }
    int run = (tid > 0) ? partial[tid - 1] : 0;
    for (int i = 0; i < chunk; i++) {
        int idx = start + i;
        if (idx < n) { offsets[idx] = run; run += counts[idx]; }
    }
    if (tid == 1023) offsets[n] = partial[1023];
}

__global__ void build_edges_kernel(const int* __restrict__ src, const int* __restrict__ dst,
                                   const int* __restrict__ offsets, int* __restrict__ cursor,
                                   int* __restrict__ ssrc, int E) {
    int e = blockIdx.x * blockDim.x + threadIdx.x;
    if (e >= E) return;
    int d = dst[e];
    int pos = offsets[d] + atomicAdd(&cursor[d], 1);
    ssrc[pos] = src[e];
}

// fused: features fp32 -> bf16 * inv_deg[row]  |  W1/W2/W3 -> swizzled bf16 panels
// Bsw layout: [k/32][n][k%32]
__global__ void prep_kernel(const float* __restrict__ features, const float* __restrict__ inv,
                            const float* __restrict__ W1, const float* __restrict__ W2,
                            const float* __restrict__ W3,
                            uint16_t* __restrict__ fbf, uint16_t* __restrict__ W1s,
                            uint16_t* __restrict__ W2s, uint16_t* __restrict__ W3s, int N) {
    int idx = blockIdx.x * blockDim.x + threadIdx.x;
    int nc = N * (INF / 4);                 // float4 groups of features
    if (idx < nc) {
        int base = idx * 4;
        int row = base >> 7;                // /128
        float s = inv[row];
        float4 v = *(const float4*)&features[base];
        ushort4 o;
        o.x = f2bf(v.x * s); o.y = f2bf(v.y * s);
        o.z = f2bf(v.z * s); o.w = f2bf(v.w * s);
        *(ushort4*)&fbf[base] = o;
        return;
    }
    idx -= nc;
    if (idx < INF * HIDF) {
        int k = idx >> 8, n = idx & 255;
        W1s[((size_t)(k >> 5) * 256 + n) * 32 + (k & 31)] = f2bf(W1[idx]);
        return;
    }
    idx -= INF * HIDF;
    if (idx < HIDF * HIDF) {
        int k = idx >> 8, n = idx & 255;
        W2s[((size_t)(k >> 5) * 256 + n) * 32 + (k & 31)] = f2bf(W2[idx]);
        return;
    }
    idx -= HIDF * HIDF;
    if (idx < HIDF * HIDF) {
        int k = idx >> 8, n = idx & 255;
        W3s[((size_t)(k >> 5) * 256 + n) * 32 + (k & 31)] = f2bf(W3[idx]);
    }
}

// ---------------- aggregation ----------------
// 256-wide rows (512 B): wave halves, each half covers a full row with 32x16B
// loads -> 2 edges in flight per issue slot, 8-edge unroll.
__global__ __launch_bounds__(256) void aggregate256(
    const uint16_t* __restrict__ hs, const int* __restrict__ offsets,
    const int* __restrict__ ssrc, uint16_t* __restrict__ out, int n) {
    const int lane = threadIdx.x & 63, wid = threadIdx.x >> 6;
    const int half = lane >> 5, l32 = lane & 31;
    const int node = blockIdx.x * 4 + wid;
    if (node >= n) return;
    const int beg = offsets[node], end = offsets[node + 1];
    float a0 = 0, a1 = 0, a2 = 0, a3 = 0, a4 = 0, a5 = 0, a6 = 0, a7 = 0;
    const size_t col = (size_t)l32 * 8;
    int e = beg + half;
    for (; e + 6 < end; e += 8) {
        int s0 = ssrc[e], s1 = ssrc[e + 2], s2 = ssrc[e + 4], s3 = ssrc[e + 6];
        uint4 r0 = *(const uint4*)&hs[(size_t)s0 * 256 + col];
        uint4 r1 = *(const uint4*)&hs[(size_t)s1 * 256 + col];
        uint4 r2 = *(const uint4*)&hs[(size_t)s2 * 256 + col];
        uint4 r3 = *(const uint4*)&hs[(size_t)s3 * 256 + col];
        a0 += bf_lo(r0.x) + bf_lo(r1.x) + bf_lo(r2.x) + bf_lo(r3.x);
        a1 += bf_hi(r0.x) + bf_hi(r1.x) + bf_hi(r2.x) + bf_hi(r3.x);
        a2 += bf_lo(r0.y) + bf_lo(r1.y) + bf_lo(r2.y) + bf_lo(r3.y);
        a3 += bf_hi(r0.y) + bf_hi(r1.y) + bf_hi(r2.y) + bf_hi(r3.y);
        a4 += bf_lo(r0.z) + bf_lo(r1.z) + bf_lo(r2.z) + bf_lo(r3.z);
        a5 += bf_hi(r0.z) + bf_hi(r1.z) + bf_hi(r2.z) + bf_hi(r3.z);
        a6 += bf_lo(r0.w) + bf_lo(r1.w) + bf_lo(r2.w) + bf_lo(r3.w);
        a7 += bf_hi(r0.w) + bf_hi(r1.w) + bf_hi(r2.w) + bf_hi(r3.w);
    }
    for (; e < end; e += 2) {
        uint4 r = *(const uint4*)&hs[(size_t)ssrc[e] * 256 + col];
        a0 += bf_lo(r.x); a1 += bf_hi(r.x); a2 += bf_lo(r.y); a3 += bf_hi(r.y);
        a4 += bf_lo(r.z); a5 += bf_hi(r.z); a6 += bf_lo(r.w); a7 += bf_hi(r.w);
    }
    a0 += __shfl_down(a0, 32, 64); a1 += __shfl_down(a1, 32, 64);
    a2 += __shfl_down(a2, 32, 64); a3 += __shfl_down(a3, 32, 64);
    a4 += __shfl_down(a4, 32, 64); a5 += __shfl_down(a5, 32, 64);
    a6 += __shfl_down(a6, 32, 64); a7 += __shfl_down(a7, 32, 64);
    if (half == 0) {
        uint4 o;
        o.x = pack2(a0, a1); o.y = pack2(a2, a3);
        o.z = pack2(a4, a5); o.w = pack2(a6, a7);
        *(uint4*)&out[(size_t)node * 256 + col] = o;
    }
}

// 128-wide rows (256 B): wave quarters -> 4 edges in flight, 8-edge unroll.
__global__ __launch_bounds__(256) void aggregate128(
    const uint16_t* __restrict__ hs, const int* __restrict__ offsets,
    const int* __restrict__ ssrc, uint16_t* __restrict__ out, int n) {
    const int lane = threadIdx.x & 63, wid = threadIdx.x >> 6;
    const int q = lane >> 4, l16 = lane & 15;
    const int node = blockIdx.x * 4 + wid;
    if (node >= n) return;
    const int beg = offsets[node], end = offsets[node + 1];
    float a0 = 0, a1 = 0, a2 = 0, a3 = 0, a4 = 0, a5 = 0, a6 = 0, a7 = 0;
    const size_t col = (size_t)l16 * 8;
    int e = beg + q;
    for (; e + 4 < end; e += 8) {
        int s0 = ssrc[e], s1 = ssrc[e + 4];
        uint4 r0 = *(const uint4*)&hs[(size_t)s0 * 128 + col];
        uint4 r1 = *(const uint4*)&hs[(size_t)s1 * 128 + col];
        a0 += bf_lo(r0.x) + bf_lo(r1.x); a1 += bf_hi(r0.x) + bf_hi(r1.x);
        a2 += bf_lo(r0.y) + bf_lo(r1.y); a3 += bf_hi(r0.y) + bf_hi(r1.y);
        a4 += bf_lo(r0.z) + bf_lo(r1.z); a5 += bf_hi(r0.z) + bf_hi(r1.z);
        a6 += bf_lo(r0.w) + bf_lo(r1.w); a7 += bf_hi(r0.w) + bf_hi(r1.w);
    }
    for (; e < end; e += 4) {
        uint4 r = *(const uint4*)&hs[(size_t)ssrc[e] * 128 + col];
        a0 += bf_lo(r.x); a1 += bf_hi(r.x); a2 += bf_lo(r.y); a3 += bf_hi(r.y);
        a4 += bf_lo(r.z); a5 += bf_hi(r.z); a6 += bf_lo(r.w); a7 += bf_hi(r.w);
    }
    a0 += __shfl_down(a0, 16, 64); a1 += __shfl_down(a1, 16, 64);
    a2 += __shfl_down(a2, 16, 64); a3 += __shfl_down(a3, 16, 64);
    a4 += __shfl_down(a4, 16, 64); a5 += __shfl_down(a5, 16, 64);
    a6 += __shfl_down(a6, 16, 64); a7 += __shfl_down(a7, 16, 64);
    a0 += __shfl_down(a0, 32, 64); a1 += __shfl_down(a1, 32, 64);
    a2 += __shfl_down(a2, 32, 64); a3 += __shfl_down(a3, 32, 64);
    a4 += __shfl_down(a4, 32, 64); a5 += __shfl_down(a5, 32, 64);
    a6 += __shfl_down(a6, 32, 64); a7 += __shfl_down(a7, 32, 64);
    if (lane < 16) {
        uint4 o;
        o.x = pack2(a0, a1); o.y = pack2(a2, a3);
        o.z = pack2(a4, a5); o.w = pack2(a6, a7);
        *(uint4*)&out[(size_t)node * 128 + col] = o;
    }
}

// ---------------- MFMA bf16 GEMM, LDS-free (layers 1-2) ----------------
__global__ __launch_bounds__(256) void gemm_mfma(
    const uint16_t* __restrict__ A, const uint16_t* __restrict__ Bsw,
    const float* __restrict__ bias, const float* __restrict__ inv,
    uint16_t* __restrict__ C, int M, int K) {
    const int lane = threadIdx.x & 63;
    const int wid = threadIdx.x >> 6;
    const int wr = wid >> 1, wc = wid & 1;
    const int quad = lane >> 4;
    const int l16 = lane & 15;

    const int m_base = blockIdx.y * 64 + wr * 32;
    const int n_base = blockIdx.x * 64 + wc * 32;

    const int r0c = min(m_base + l16, M - 1);
    const int r1c = min(m_base + 16 + l16, M - 1);

    const uint16_t* a0p = A + (size_t)r0c * K + quad * 8;
    const uint16_t* a1p = A + (size_t)r1c * K + quad * 8;
    const uint16_t* b0p = Bsw + ((size_t)(n_base + l16)) * 32 + quad * 8;
    const uint16_t* b1p = Bsw + ((size_t)(n_base + 16 + l16)) * 32 + quad * 8;

    f32x4 acc00 = {0, 0, 0, 0}, acc01 = {0, 0, 0, 0};
    f32x4 acc10 = {0, 0, 0, 0}, acc11 = {0, 0, 0, 0};

    const int panels = K >> 5;
#pragma unroll 4
    for (int p = 0; p < panels; p++) {
        bf16x8 a0 = *(const bf16x8*)(a0p + p * 32);
        bf16x8 a1 = *(const bf16x8*)(a1p + p * 32);
        bf16x8 b0 = *(const bf16x8*)(b0p + (size_t)p * 256 * 32);
        bf16x8 b1 = *(const bf16x8*)(b1p + (size_t)p * 256 * 32);
        acc00 = __builtin_amdgcn_mfma_f32_16x16x32_bf16(a0, b0, acc00, 0, 0, 0);
        acc01 = __builtin_amdgcn_mfma_f32_16x16x32_bf16(a0, b1, acc01, 0, 0, 0);
        acc10 = __builtin_amdgcn_mfma_f32_16x16x32_bf16(a1, b0, acc10, 0, 0, 0);
        acc11 = __builtin_amdgcn_mfma_f32_16x16x32_bf16(a1, b1, acc11, 0, 0, 0);
    }

    // C/D layout: col = lane&15, row = quad*4 + reg
    const int col0 = n_base + l16;
    const int col1 = col0 + 16;
    const float bv0 = bias[col0];
    const float bv1 = bias[col1];
#pragma unroll
    for (int reg = 0; reg < 4; reg++) {
        int row0 = m_base + quad * 4 + reg;
        int row1 = row0 + 16;
        if (row0 < M) {
            float s = inv[row0];
            C[(size_t)row0 * 256 + col0] = f2bf(fmaxf(acc00[reg] + bv0, 0.f) * s);
            C[(size_t)row0 * 256 + col1] = f2bf(fmaxf(acc01[reg] + bv1, 0.f) * s);
        }
        if (row1 < M) {
            float s = inv[row1];
            C[(size_t)row1 * 256 + col0] = f2bf(fmaxf(acc10[reg] + bv0, 0.f) * s);
            C[(size_t)row1 * 256 + col1] = f2bf(fmaxf(acc11[reg] + bv1, 0.f) * s);
        }
    }
}

// ---------------- layer-3 GEMM with fused heads (no C store) ----------------
// pi[row] = sum_col (acc+b3[col]) * Wp[col] + bp  -> global atomics (out zeroed)
// colsum[col] = sum_row (acc+b3[col])             -> LDS then global atomics
__global__ __launch_bounds__(256) void gemm_heads(
    const uint16_t* __restrict__ A, const uint16_t* __restrict__ Bsw,
    const float* __restrict__ b3, const float* __restrict__ Wp,
    const float* __restrict__ bp, float* __restrict__ pi_out,
    float* __restrict__ colsum, int M, int K) {
    __shared__ float lds_cs[64];
    if (threadIdx.x < 64) lds_cs[threadIdx.x] = 0.f;
    __syncthreads();

    const int lane = threadIdx.x & 63;
    const int wid = threadIdx.x >> 6;
    const int wr = wid >> 1, wc = wid & 1;
    const int quad = lane >> 4;
    const int l16 = lane & 15;

    const int m_base = blockIdx.y * 64 + wr * 32;
    const int n_base = blockIdx.x * 64 + wc * 32;

    const int r0c = min(m_base + l16, M - 1);
    const int r1c = min(m_base + 16 + l16, M - 1);

    const uint16_t* a0p = A + (size_t)r0c * K + quad * 8;
    const uint16_t* a1p = A + (size_t)r1c * K + quad * 8;
    const uint16_t* b0p = Bsw + ((size_t)(n_base + l16)) * 32 + quad * 8;
    const uint16_t* b1p = Bsw + ((size_t)(n_base + 16 + l16)) * 32 + quad * 8;

    f32x4 acc00 = {0, 0, 0, 0}, acc01 = {0, 0, 0, 0};
    f32x4 acc10 = {0, 0, 0, 0}, acc11 = {0, 0, 0, 0};

    const int panels = K >> 5;
#pragma unroll 4
    for (int p = 0; p < panels; p++) {
        bf16x8 a0 = *(const bf16x8*)(a0p + p * 32);
        bf16x8 a1 = *(const bf16x8*)(a1p + p * 32);
        bf16x8 b0 = *(const bf16x8*)(b0p + (size_t)p * 256 * 32);
        bf16x8 b1 = *(const bf16x8*)(b1p + (size_t)p * 256 * 32);
        acc00 = __builtin_amdgcn_mfma_f32_16x16x32_bf16(a0, b0, acc00, 0, 0, 0);
        acc01 = __builtin_amdgcn_mfma_f32_16x16x32_bf16(a0, b1, acc01, 0, 0, 0);
        acc10 = __builtin_amdgcn_mfma_f32_16x16x32_bf16(a1, b0, acc10, 0, 0, 0);
        acc11 = __builtin_amdgcn_mfma_f32_16x16x32_bf16(a1, b1, acc11, 0, 0, 0);
    }

    const int col0 = n_base + l16;
    const int col1 = col0 + 16;
    const float bv0 = b3[col0], bv1 = b3[col1];
    const float wp0 = Wp[col0], wp1 = Wp[col1];
    const float bpv = bp[0];
    const bool addbias = (blockIdx.x == 0 && wc == 0);
    float cs0 = 0.f, cs1 = 0.f;

#pragma unroll
    for (int reg = 0; reg < 4; reg++) {
        int row0 = m_base + quad * 4 + reg;
        int row1 = row0 + 16;
        bool ok0 = row0 < M, ok1 = row1 < M;
        float v00 = acc00[reg] + bv0, v01 = acc01[reg] + bv1;
        float v10 = acc10[reg] + bv0, v11 = acc11[reg] + bv1;
        if (ok0) { cs0 += v00; cs1 += v01; }
        if (ok1) { cs0 += v10; cs1 += v11; }
        float p0 = v00 * wp0 + v01 * wp1;
        float p1 = v10 * wp0 + v11 * wp1;
#pragma unroll
        for (int m = 1; m < 16; m <<= 1) {
            p0 += __shfl_xor(p0, m, 64);
            p1 += __shfl_xor(p1, m, 64);
        }
        if (l16 == 0) {
            if (ok0) atomicAdd(&pi_out[row0], p0 + (addbias ? bpv : 0.f));
            if (ok1) atomicAdd(&pi_out[row1], p1 + (addbias ? bpv : 0.f));
        }
    }

    cs0 += __shfl_xor(cs0, 16, 64); cs0 += __shfl_xor(cs0, 32, 64);
    cs1 += __shfl_xor(cs1, 16, 64); cs1 += __shfl_xor(cs1, 32, 64);
    if (quad == 0) {
        atomicAdd(&lds_cs[wc * 32 + l16], cs0);
        atomicAdd(&lds_cs[wc * 32 + 16 + l16], cs1);
    }
    __syncthreads();
    if (threadIdx.x < 64)
        atomicAdd(&colsum[blockIdx.x * 64 + threadIdx.x], lds_cs[threadIdx.x]);
}

// ---------------- V head finisher ----------------
__global__ void v_kernel(const float* __restrict__ colsum, const float* __restrict__ Wv,
                         const float* __restrict__ bv, float* __restrict__ out, float invN) {
    int lane = threadIdx.x;  // 64
    float v = 0.0f;
#pragma unroll
    for (int i = 0; i < 4; i++) v += colsum[lane + 64 * i] * Wv[lane + 64 * i];
#pragma unroll
    for (int o = 32; o > 0; o >>= 1) v += __shfl_down(v, o, 64);
    if (lane == 0) out[0] = v * invN + bv[0];
}

// ---------------- launch ----------------

extern "C" void kernel_launch(void* const* d_in, const int* in_sizes, int n_in,
                              void* d_out, int out_size, void* d_ws, size_t ws_size,
                              hipStream_t stream) {
    const float* features = (const float*)d_in[0];
    const int*   src      = (const int*)d_in[1];
    const int*   dst      = (const int*)d_in[2];
    const float* W1 = (const float*)d_in[3];
    const float* b1 = (const float*)d_in[4];
    const float* W2 = (const float*)d_in[5];
    const float* b2 = (const float*)d_in[6];
    const float* W3 = (const float*)d_in[7];
    const float* b3 = (const float*)d_in[8];
    const float* Wp = (const float*)d_in[9];
    const float* bp = (const float*)d_in[10];
    const float* Wv = (const float*)d_in[11];
    const float* bv = (const float*)d_in[12];
    float* out = (float*)d_out;

    const int N = in_sizes[0] / INF;   // 10000
    const int E = in_sizes[1];         // 320000

    char* p = (char*)d_ws;
    auto alloc = [&](size_t bytes) -> void* {
        void* r = (void*)p;
        p += (bytes + 511) & ~(size_t)511;
        return r;
    };
    // zero-region first (single memset): odeg, counts, cursor, colsum
    int*      odeg    = (int*)alloc((size_t)N * 4);
    int*      counts  = (int*)alloc((size_t)N * 4);
    int*      cursor  = (int*)alloc((size_t)N * 4);
    float*    colsum  = (float*)alloc(HIDF * 4);
    size_t zero_bytes = (size_t)((char*)(colsum + HIDF) - (char*)d_ws);
    // rest
    int*      offsets = (int*)alloc((size_t)(N + 1) * 4);
    int*      ssrc    = (int*)alloc((size_t)E * 4);
    float*    invd    = (float*)alloc((size_t)N * 4);
    uint16_t* fbf     = (uint16_t*)alloc((size_t)N * INF * 2);
    uint16_t* ab      = (uint16_t*)alloc((size_t)N * HIDF * 2);  // aggregated (GEMM A)
    uint16_t* hb      = (uint16_t*)alloc((size_t)N * HIDF * 2);  // layer output
    uint16_t* W1s     = (uint16_t*)alloc((size_t)INF * HIDF * 2);
    uint16_t* W2s     = (uint16_t*)alloc((size_t)HIDF * HIDF * 2);
    uint16_t* W3s     = (uint16_t*)alloc((size_t)HIDF * HIDF * 2);

    hipMemsetAsync(d_ws, 0, zero_bytes, stream);
    hipMemsetAsync(d_out, 0, (size_t)out_size * 4, stream);

    const int eb = (E + 255) / 256;
    hist_kernel<<<eb, 256, 0, stream>>>(src, dst, odeg, counts, E);
    scan_kernel<<<1, 1024, 0, stream>>>(counts, offsets, odeg, invd, N);
    build_edges_kernel<<<eb, 256, 0, stream>>>(src, dst, offsets, cursor, ssrc, E);
    {
        int total = N * (INF / 4) + INF * HIDF + 2 * HIDF * HIDF;
        prep_kernel<<<(total + 255) / 256, 256, 0, stream>>>(
            features, invd, W1, W2, W3, fbf, W1s, W2s, W3s, N);
    }

    dim3 ggrid(4, (N + 63) / 64);   // 4 x 157

    aggregate128<<<(N + 3) / 4, 256, 0, stream>>>(fbf, offsets, ssrc, ab, N);
    gemm_mfma<<<ggrid, 256, 0, stream>>>(ab, W1s, b1, invd, hb, N, INF);
    aggregate256<<<(N + 3) / 4, 256, 0, stream>>>(hb, offsets, ssrc, ab, N);
    gemm_mfma<<<ggrid, 256, 0, stream>>>(ab, W2s, b2, invd, hb, N, HIDF);
    aggregate256<<<(N + 3) / 4, 256, 0, stream>>>(hb, offsets, ssrc, ab, N);
    gemm_heads<<<ggrid, 256, 0, stream>>>(ab, W3s, b3, Wp, bp, out, colsum, N, HIDF);

    v_kernel<<<1, 64, 0, stream>>>(colsum, Wv, bv, out + N, 1.0f / (float)N);
}